// Round 4
// baseline (324.337 us; speedup 1.0000x reference)
//
#include <hip/hip_runtime.h>
#include <stdint.h>

// Problem constants
#define B_SZ  4
#define T_SEQ 2048
#define DIM   1024
#define NH    16
#define HD    64
#define M_TOT (B_SZ * T_SEQ)   // 8192

typedef unsigned short u16;
typedef unsigned long long u64;
typedef __attribute__((ext_vector_type(8))) __bf16 bf16x8;   // MFMA A/B frag (4 VGPR)
typedef __attribute__((ext_vector_type(4))) float  floatx4;  // MFMA C/D frag 16x16
typedef __attribute__((ext_vector_type(16))) float floatx16; // MFMA C/D frag 32x32

#define SCL_Q (0.125f * 1.44269504089f)   // 1/sqrt(HD) * log2(e), folded into q

__device__ __forceinline__ u16 f2bf(float f) {
  union { float f; uint32_t u; } v; v.f = f;
  uint32_t r = v.u + 0x7fffu + ((v.u >> 16) & 1u);   // RNE
  return (u16)(r >> 16);
}

// async global->LDS, 16B per lane; LDS dest = uniform base + lane*16
__device__ __forceinline__ void gl_lds16(const void* g, void* l) {
  __builtin_amdgcn_global_load_lds(
      (const __attribute__((address_space(1))) uint32_t*)g,
      (__attribute__((address_space(3))) uint32_t*)l, 16, 0, 0);
}

// ---------------------------------------------------------------- converts
__global__ __launch_bounds__(256) void cvt_all(
    const float* __restrict__ s0, const float* __restrict__ s1,
    const float* __restrict__ s2, const float* __restrict__ s3,
    const float* __restrict__ s4, const float* __restrict__ s5,
    const float* __restrict__ s6,
    u16* __restrict__ d0, u16* __restrict__ d1, u16* __restrict__ d2,
    u16* __restrict__ d3, u16* __restrict__ d4, u16* __restrict__ d5,
    u16* __restrict__ d6) {
  const float* s; u16* d; int n;
  switch (blockIdx.y) {
    case 0: s = s0; d = d0; n = DIM * DIM; break;
    case 1: s = s1; d = d1; n = DIM * DIM; break;
    case 2: s = s2; d = d2; n = DIM * DIM; break;
    case 3: s = s3; d = d3; n = DIM * DIM; break;
    case 4: s = s4; d = d4; n = M_TOT * DIM; break;
    case 5: s = s5; d = d5; n = M_TOT * DIM; break;
    default: s = s6; d = d6; n = M_TOT * DIM; break;
  }
  int i = (blockIdx.x * 256 + threadIdx.x) * 8;
  if (i >= n) return;
  float4 a = *(const float4*)(s + i);
  float4 b = *(const float4*)(s + i + 4);
  uint4 o;
  o.x = (uint32_t)f2bf(a.x) | ((uint32_t)f2bf(a.y) << 16);
  o.y = (uint32_t)f2bf(a.z) | ((uint32_t)f2bf(a.w) << 16);
  o.z = (uint32_t)f2bf(b.x) | ((uint32_t)f2bf(b.y) << 16);
  o.w = (uint32_t)f2bf(b.z) | ((uint32_t)f2bf(b.w) << 16);
  *(uint4*)(d + i) = o;
}

// ---------------------------------------------------------------- QKV GEMM v4b
// 8-phase 256x256 template (T2 swizzle + T3 phase-split + T4 counted vmcnt +
// T5 setprio). BK=64, 8 waves (2M x 4N), 512 thr, 128 KiB LDS (2 K-tile dbuf).
// v4 BUG FIXED: A(t+2) must stage into the buffer holding A(t) (same parity
// as Ac: (t+2)&1 == t&1) — v4 staged it over A(t+1). One-line fix.
// Stage stream: ph0/ph1 -> B halves of tile t+1; ph3 -> both A halves of
// tile t+2 (5-phase lead). Boundary s_waitcnt vmcnt(4) once per K-tile
// (retires A(t+1)+B(t+1), keeps A(t+2) in flight); vmcnt(0) only at the
// last two boundaries. Overwrite safety: A(t) last ds_read completes before
// end-of-ph2 barrier (lgkmcnt(0) precedes MFMA), ph3 stage is after it;
// B(t+1) targets the opposite B buffer; B(t-1) reads complete before the
// tile-boundary barrier.
#define BKG  64
#define NT_K (DIM / BKG)   // 16

__device__ __forceinline__ void stage_half(
    const u16* __restrict__ src, int grow0, int k0, u16* ldsbase,
    int wave, int lr8, int lc8) {
#pragma unroll
  for (int j = 0; j < 2; ++j) {
    int rb = j * 64 + wave * 8;           // local row base within the half
    int R  = grow0 + rb + lr8;            // global matrix row (per-lane)
    gl_lds16(src + (size_t)R * DIM + k0 + ((lc8 ^ lr8) * 8),
             ldsbase + (size_t)rb * 64);  // wave-uniform dest
  }
}

__global__ __launch_bounds__(512, 2) void gemm_qkv(
    const u16* __restrict__ Qb, const u16* __restrict__ Kb,
    const u16* __restrict__ Vb,
    const u16* __restrict__ Wq, const u16* __restrict__ Wk,
    const u16* __restrict__ Wv,
    const float* __restrict__ bq, const float* __restrict__ bk,
    const float* __restrict__ bv,
    u16* __restrict__ qo, u16* __restrict__ ko, u16* __restrict__ vo) {
  const u16* A; const u16* Bw; const float* bias; u16* Co;
  if (blockIdx.z == 0)      { A = Qb; Bw = Wq; bias = bq; Co = qo; }
  else if (blockIdx.z == 1) { A = Kb; Bw = Wk; bias = bk; Co = ko; }
  else                      { A = Vb; Bw = Wv; bias = bv; Co = vo; }

  __shared__ u16 sh[4 * 256 * 64];   // Ab[0],Ab[1],Bb[0],Bb[1] : 128 KiB
  u16* const Ab0 = sh;
  u16* const Ab1 = sh + 256 * 64;
  u16* const Bb0 = sh + 2 * 256 * 64;
  u16* const Bb1 = sh + 3 * 256 * 64;

  const int tid  = threadIdx.x;
  const int wave = tid >> 6, lane = tid & 63;
  const int quad = lane >> 4, l16 = lane & 15;
  const int lr8 = lane >> 3, lc8 = lane & 7;
  const int wm = wave >> 2, wn = wave & 3;          // 2M x 4N
  const int m0 = blockIdx.x * 256, n0 = blockIdx.y * 256;

  const floatx4 FZ = {0.f, 0.f, 0.f, 0.f};
  floatx4 acc[8][4];
#pragma unroll
  for (int mt = 0; mt < 8; ++mt)
#pragma unroll
    for (int nt = 0; nt < 4; ++nt) acc[mt][nt] = FZ;

  // ---- prologue: A(0) both halves, B(0) both halves, A(1) both halves
  stage_half(A,  m0,       0,   Ab0,            wave, lr8, lc8);
  stage_half(A,  m0 + 128, 0,   Ab0 + 128 * 64, wave, lr8, lc8);
  stage_half(Bw, n0,       0,   Bb0,            wave, lr8, lc8);
  stage_half(Bw, n0 + 128, 0,   Bb0 + 128 * 64, wave, lr8, lc8);
  stage_half(A,  m0,       BKG, Ab1,            wave, lr8, lc8);
  stage_half(A,  m0 + 128, BKG, Ab1 + 128 * 64, wave, lr8, lc8);
  asm volatile("s_waitcnt vmcnt(4)" ::: "memory");   // tile0 landed; A(1) fly
  __builtin_amdgcn_s_barrier();
  __builtin_amdgcn_sched_barrier(0);

  bf16x8 afr[4][2];   // retained A frags (one m-quad, K=64)
  bf16x8 bfr[2][2];   // B frags for current n-quad

  for (int t = 0; t < NT_K; ++t) {
    u16* const Ac = (t & 1) ? Ab1 : Ab0;
    u16* const Bc = (t & 1) ? Bb1 : Bb0;
    u16* const An = (t & 1) ? Ab1 : Ab0;   // A(t+2) target == Ac parity (FIX)
    u16* const Bn = (t & 1) ? Bb0 : Bb1;   // B(t+1) target (opposite parity)

#pragma unroll
    for (int ph = 0; ph < 4; ++ph) {
      const int mq = ph >> 1, nq = ph & 1;
      // ---- ds reads for this phase
      if (nq == 0) {   // new A m-quad (8 reads)
#pragma unroll
        for (int mt = 0; mt < 4; ++mt) {
          int ra = wm * 128 + mq * 64 + mt * 16 + l16;
#pragma unroll
          for (int kk = 0; kk < 2; ++kk)
            afr[mt][kk] = *(const bf16x8*)
                &Ac[ra * 64 + (((kk * 4 + quad) ^ (ra & 7)) * 8)];
        }
      }
      // B n-quad (4 reads, re-read each phase)
#pragma unroll
      for (int nt = 0; nt < 2; ++nt) {
        int rb = wn * 64 + nq * 32 + nt * 16 + l16;
#pragma unroll
        for (int kk = 0; kk < 2; ++kk)
          bfr[nt][kk] = *(const bf16x8*)
              &Bc[rb * 64 + (((kk * 4 + quad) ^ (rb & 7)) * 8)];
      }
      // ---- stage issue for this phase
      if (ph == 0 && t + 1 < NT_K)
        stage_half(Bw, n0,       (t + 1) * BKG, Bn,            wave, lr8, lc8);
      if (ph == 1 && t + 1 < NT_K)
        stage_half(Bw, n0 + 128, (t + 1) * BKG, Bn + 128 * 64, wave, lr8, lc8);
      if (ph == 3 && t + 2 < NT_K) {
        stage_half(A, m0,       (t + 2) * BKG, An,            wave, lr8, lc8);
        stage_half(A, m0 + 128, (t + 2) * BKG, An + 128 * 64, wave, lr8, lc8);
      }
      // ---- sync + compute
      __builtin_amdgcn_s_barrier();
      __builtin_amdgcn_sched_barrier(0);
      asm volatile("s_waitcnt lgkmcnt(0)" ::: "memory");
      __builtin_amdgcn_sched_barrier(0);
      __builtin_amdgcn_s_setprio(1);
#pragma unroll
      for (int mt = 0; mt < 4; ++mt)
#pragma unroll
        for (int nt = 0; nt < 2; ++nt)
#pragma unroll
          for (int kk = 0; kk < 2; ++kk)
            acc[mq * 4 + mt][nq * 2 + nt] =
                __builtin_amdgcn_mfma_f32_16x16x32_bf16(
                    afr[mt][kk], bfr[nt][kk], acc[mq * 4 + mt][nq * 2 + nt],
                    0, 0, 0);
      __builtin_amdgcn_s_setprio(0);
      // ---- phase-exit barrier; K-tile boundary adds the counted vmcnt
      if (ph == 3) {
        if (t + 1 >= NT_K) break;   // last tile: no more syncs needed
        if (t + 2 < NT_K) asm volatile("s_waitcnt vmcnt(4)" ::: "memory");
        else              asm volatile("s_waitcnt vmcnt(0)" ::: "memory");
      }
      __builtin_amdgcn_s_barrier();
      __builtin_amdgcn_sched_barrier(0);
    }
  }

  // ---- epilogue
  if (blockIdx.z == 2) {
    // V: transposed store to [B,H,HD,T], 8B packed (4 consecutive t)
#pragma unroll
    for (int nt = 0; nt < 4; ++nt) {
      int n = n0 + wn * 64 + nt * 16 + l16;
      float bb = bias[n];
      int hh = n >> 6, hd = n & 63;
#pragma unroll
      for (int mt = 0; mt < 8; ++mt) {
        int mbase = m0 + wm * 128 + mt * 16 + quad * 4;
        int b = mbase >> 11, tq = mbase & (T_SEQ - 1);
        u64 pk = 0;
#pragma unroll
        for (int r = 0; r < 4; ++r)
          pk |= (u64)f2bf(acc[mt][nt][r] + bb) << (16 * r);
        *(u64*)&Co[((size_t)((b * NH + hh) * HD + hd)) * T_SEQ + tq] = pk;
      }
    }
  } else {
    // Q/K: +bias (Q also * SCL_Q), bf16, scatter to [B,H,T,HD]
    const float sc = (blockIdx.z == 0) ? SCL_Q : 1.0f;
#pragma unroll
    for (int nt = 0; nt < 4; ++nt) {
      int n = n0 + wn * 64 + nt * 16 + l16;
      float bb = bias[n];
      int hh = n >> 6, hd = n & 63;
#pragma unroll
      for (int mt = 0; mt < 8; ++mt) {
#pragma unroll
        for (int r = 0; r < 4; ++r) {
          int m = m0 + wm * 128 + mt * 16 + quad * 4 + r;
          int b = m >> 11, tq = m & (T_SEQ - 1);
          Co[((size_t)(b * NH + hh) * T_SEQ + tq) * HD + hd] =
              f2bf((acc[mt][nt][r] + bb) * sc);
        }
      }
    }
  }
}

// ---------------------------------------------------------------- flash attn
// v3 (unchanged): 32x32x16 MFMA, permlane P-transpose, fixed-max softmax,
// 8 waves / 256-q-row tiles, 3-deep K/V pipeline with counted vmcnt(2).
__global__ __launch_bounds__(512, 2) void flash_attn(
    const u16* __restrict__ qp, const u16* __restrict__ kp,
    const u16* __restrict__ vp, u16* __restrict__ ao) {
  const int bh = blockIdx.x;                       // 0..63
  const int y = blockIdx.y;                        // 0..7
  const int qt = (y < 4) ? (7 - y) : (y - 4);      // heavy first + pairing
  const int b = bh >> 4, h = bh & 15;
  const u16* Qg = qp + (size_t)bh * T_SEQ * HD;
  const u16* Kg = kp + (size_t)bh * T_SEQ * HD;
  const u16* Vg = vp + (size_t)bh * HD * T_SEQ;    // [hd][t]

  __shared__ u16 lds[6][64 * 64];   // {K,V} x 3-deep, 48 KB

  const int tid = threadIdx.x, wave = tid >> 6, lane = tid & 63;
  const int hi = lane >> 5, c31 = lane & 31;
  const int lr8 = lane >> 3, lc8 = lane & 7;

  const int qrow = qt * 256 + wave * 32 + c31;     // this lane's global q

  // ---- Q B-frags straight from global FIRST (oldest vmem ops)
  bf16x8 bq[4];
#pragma unroll
  for (int cth = 0; cth < 4; ++cth)
    bq[cth] = *(const bf16x8*)(Qg + (size_t)qrow * HD + cth * 16 + hi * 8);

  const int nkb = 4 * qt + 4;                      // kv tiles (>=4)
  const int srow = wave * 8 + lr8;
  const int ssc = lc8 ^ (srow & 7);

  // ---- prologue: stage kv-tiles 0 and 1 (2 vmem ops per wave per tile)
  gl_lds16(Kg + (size_t)srow * HD + ssc * 8, &lds[0][wave * 8 * 64]);
  gl_lds16(Vg + (size_t)srow * T_SEQ + ssc * 8, &lds[1][wave * 8 * 64]);
  gl_lds16(Kg + (size_t)(64 + srow) * HD + ssc * 8, &lds[2][wave * 8 * 64]);
  gl_lds16(Vg + (size_t)srow * T_SEQ + 64 + ssc * 8, &lds[3][wave * 8 * 64]);

  asm volatile("" :: "v"(bq[0]), "v"(bq[1]), "v"(bq[2]), "v"(bq[3]));

  floatx16 o0, o1;   // O^T accum: rows hd 0..31 / 32..63, col q = c31
#pragma unroll
  for (int i = 0; i < 16; ++i) { o0[i] = 0.f; o1[i] = 0.f; }
  float l_p = 0.f;   // lane-local unnormalized softmax denominator

  int koff[4];
#pragma unroll
  for (int x = 0; x < 4; ++x)
    koff[x] = c31 * 64 + (((x * 2 + hi) ^ (c31 & 7)) * 8);

  const int qwmin = qt * 256 + wave * 32;       // wave's min q
  const int qwmax = qwmin + 31;                 // wave's max q
  int pc_ = 0;        // compute buffer (pair) index
  int ps_ = 2;        // next stage buffer (pair) index
  for (int kb = 0; kb < nkb; ++kb) {
    if (kb + 1 < nkb) asm volatile("s_waitcnt vmcnt(2)" ::: "memory");
    else              asm volatile("s_waitcnt vmcnt(0)" ::: "memory");
    __builtin_amdgcn_s_barrier();
    __builtin_amdgcn_sched_barrier(0);

    if (kb + 2 < nkb) {   // stage tile kb+2 into buf ps_
      const u16* Kgk = Kg + (size_t)(kb + 2) * 64 * HD;
      const u16* Vgk = Vg + (size_t)(kb + 2) * 64;
      gl_lds16(Kgk + (size_t)srow * HD + ssc * 8, &lds[ps_ * 2][wave * 8 * 64]);
      gl_lds16(Vgk + (size_t)srow * T_SEQ + ssc * 8,
               &lds[ps_ * 2 + 1][wave * 8 * 64]);
      ps_ = (ps_ == 2) ? 0 : ps_ + 1;
    }

    if (kb * 64 <= qwmax) {
      const u16* Ks = &lds[pc_ * 2][0];
      const u16* Vs = &lds[pc_ * 2 + 1][0];

      floatx16 s0, s1;
#pragma unroll
      for (int i = 0; i < 16; ++i) { s0[i] = 0.f; s1[i] = 0.f; }
#pragma unroll
      for (int cth = 0; cth < 4; ++cth) {
        bf16x8 ka = *(const bf16x8*)&Ks[koff[cth]];
        bf16x8 kb2 = *(const bf16x8*)&Ks[koff[cth] + 32 * 64];
        s0 = __builtin_amdgcn_mfma_f32_32x32x16_bf16(ka, bq[cth], s0, 0, 0, 0);
        s1 = __builtin_amdgcn_mfma_f32_32x32x16_bf16(kb2, bq[cth], s1, 0, 0, 0);
      }

      if (kb * 64 + 63 > qwmin) {
        int kvb = kb * 64 + 4 * hi;
#pragma unroll
        for (int r = 0; r < 16; ++r) {
          int kvr = kvb + (r & 3) + 8 * (r >> 2);
          if (kvr > qrow)      s0[r] = -3e38f;
          if (kvr + 32 > qrow) s1[r] = -3e38f;
        }
      }

      uint32_t pk0[8], pk1[8];
      float rs = 0.f;
#pragma unroll
      for (int rr = 0; rr < 8; ++rr) {
        union { float f; uint32_t u; } x0, x1, y0, y1;
        x0.f = __builtin_amdgcn_exp2f(s0[2 * rr]);
        x1.f = __builtin_amdgcn_exp2f(s0[2 * rr + 1]);
        y0.f = __builtin_amdgcn_exp2f(s1[2 * rr]);
        y1.f = __builtin_amdgcn_exp2f(s1[2 * rr + 1]);
        rs += (x0.f + x1.f) + (y0.f + y1.f);
        pk0[rr] = __builtin_amdgcn_perm(x1.u, x0.u, 0x07060302);  // bf16 pair
        pk1[rr] = __builtin_amdgcn_perm(y1.u, y0.u, 0x07060302);
      }
      l_p += rs;

#pragma unroll
      for (int cc = 0; cc < 4; ++cc) {
        const uint32_t* pks = (cc & 2) ? pk1 : pk0;
        const int e4 = (cc & 1) * 4;
        auto r0 = __builtin_amdgcn_permlane32_swap(pks[e4 + 0], pks[e4 + 2],
                                                   false, false);
        auto r1 = __builtin_amdgcn_permlane32_swap(pks[e4 + 1], pks[e4 + 3],
                                                   false, false);
        union { uint32_t u[4]; bf16x8 v; } bp;
        bp.u[0] = r0[0]; bp.u[1] = r1[0]; bp.u[2] = r0[1]; bp.u[3] = r1[1];
        bf16x8 va = *(const bf16x8*)&Vs[koff[cc]];
        bf16x8 vb = *(const bf16x8*)&Vs[koff[cc] + 32 * 64];
        o0 = __builtin_amdgcn_mfma_f32_32x32x16_bf16(va, bp.v, o0, 0, 0, 0);
        o1 = __builtin_amdgcn_mfma_f32_32x32x16_bf16(vb, bp.v, o1, 0, 0, 0);
      }
    }
    pc_ = (pc_ == 2) ? 0 : pc_ + 1;
  }

  {
    float l = l_p + __shfl_xor(l_p, 32);
    float inv = 1.0f / l;
    const size_t obase = (size_t)(b * T_SEQ + qrow) * DIM + h * HD;
#pragma unroll
    for (int u4 = 0; u4 < 4; ++u4) {
      u64 w0 = 0, w1 = 0;
#pragma unroll
      for (int r = 0; r < 4; ++r) {
        w0 |= (u64)f2bf(o0[4 * u4 + r] * inv) << (16 * r);
        w1 |= (u64)f2bf(o1[4 * u4 + r] * inv) << (16 * r);
      }
      *(u64*)&ao[obase + 8 * u4 + 4 * hi] = w0;
      *(u64*)&ao[obase + 32 + 8 * u4 + 4 * hi] = w1;
    }
  }
}

// ---------------------------------------------------------------- out GEMM
__global__ __launch_bounds__(256) void gemm_out(
    const u16* __restrict__ Ain, const u16* __restrict__ Wo,
    const float* __restrict__ bo, float* __restrict__ out) {
  __shared__ u16 As[128 * 64];
  __shared__ u16 Bs[128 * 64];

  const int tid  = threadIdx.x;
  const int wave = tid >> 6, lane = tid & 63;
  const int quad = lane >> 4, l16 = lane & 15;
  const int wm = wave >> 1, wn = wave & 1;
  const int m0 = blockIdx.x * 128, n0 = blockIdx.y * 128;

  const floatx4 FZ = {0.f, 0.f, 0.f, 0.f};
  floatx4 acc[4][4];
#pragma unroll
  for (int mt = 0; mt < 4; ++mt)
#pragma unroll
    for (int nt = 0; nt < 4; ++nt) acc[mt][nt] = FZ;

  for (int k0 = 0; k0 < DIM; k0 += BKG) {
    __syncthreads();
#pragma unroll
    for (int j = 0; j < 4; ++j) {
      int pc = j * 256 + tid;
      int r = pc >> 3, c = pc & 7;
      int sc = c ^ (r & 7);
      gl_lds16(Ain + (size_t)(m0 + r) * DIM + k0 + sc * 8,
               &As[(j * 256 + wave * 64) * 8]);
      gl_lds16(Wo  + (size_t)(n0 + r) * DIM + k0 + sc * 8,
               &Bs[(j * 256 + wave * 64) * 8]);
    }
    __syncthreads();

#pragma unroll
    for (int kk = 0; kk < 2; ++kk) {
      bf16x8 af[4], bfr[4];
#pragma unroll
      for (int mt = 0; mt < 4; ++mt) {
        int ra = wm * 64 + mt * 16 + l16;
        af[mt] = *(const bf16x8*)&As[ra * 64 + (((kk * 4 + quad) ^ (ra & 7)) * 8)];
      }
#pragma unroll
      for (int nt = 0; nt < 4; ++nt) {
        int rb = wn * 64 + nt * 16 + l16;
        bfr[nt] = *(const bf16x8*)&Bs[rb * 64 + (((kk * 4 + quad) ^ (rb & 7)) * 8)];
      }
#pragma unroll
      for (int mt = 0; mt < 4; ++mt)
#pragma unroll
        for (int nt = 0; nt < 4; ++nt)
          acc[mt][nt] = __builtin_amdgcn_mfma_f32_16x16x32_bf16(
              af[mt], bfr[nt], acc[mt][nt], 0, 0, 0);
    }
  }

#pragma unroll
  for (int nt = 0; nt < 4; ++nt) {
    int n = n0 + wn * 64 + nt * 16 + l16;
    float bb = bo[n];
#pragma unroll
    for (int mt = 0; mt < 4; ++mt)
#pragma unroll
      for (int r = 0; r < 4; ++r) {
        int m = m0 + wm * 64 + mt * 16 + quad * 4 + r;
        out[(size_t)m * DIM + n] = acc[mt][nt][r] + bb;
      }
  }
}

// ---------------------------------------------------------------- launch
extern "C" void kernel_launch(void* const* d_in, const int* in_sizes, int n_in,
                              void* d_out, int out_size, void* d_ws,
                              size_t ws_size, hipStream_t stream) {
  const float* Q  = (const float*)d_in[0];
  const float* K  = (const float*)d_in[1];
  const float* V  = (const float*)d_in[2];
  // d_in[3] = mask: tril causal, implemented analytically in flash_attn
  const float* Wq = (const float*)d_in[4];
  const float* bq = (const float*)d_in[5];
  const float* Wk = (const float*)d_in[6];
  const float* bk = (const float*)d_in[7];
  const float* Wv = (const float*)d_in[8];
  const float* bv = (const float*)d_in[9];
  const float* Wo = (const float*)d_in[10];
  const float* bo = (const float*)d_in[11];
  float* out = (float*)d_out;

  // workspace layout (u16 elements), total ~120 MiB
  u16* wqb = (u16*)d_ws;
  u16* wkb = wqb + 1048576;
  u16* wvb = wkb + 1048576;
  u16* wob = wvb + 1048576;
  u16* Qb  = wob + 1048576;             // activations bf16 [B,T,D]
  u16* Kb  = Qb + (size_t)M_TOT * DIM;
  u16* Vb  = Kb + (size_t)M_TOT * DIM;
  u16* qp  = Vb + (size_t)M_TOT * DIM;  // projected [B,H,T,HD] (q pre-scaled)
  u16* kp  = qp + (size_t)M_TOT * DIM;  // [B,H,T,HD]
  u16* vp  = kp + (size_t)M_TOT * DIM;  // [B,H,HD,T]  (pre-transposed)
  u16* aop = vp + (size_t)M_TOT * DIM;  // attn out [B,T,D] bf16

  cvt_all<<<dim3(M_TOT * DIM / 2048, 7), 256, 0, stream>>>(
      Wq, Wk, Wv, Wo, Q, K, V, wqb, wkb, wvb, wob, Qb, Kb, Vb);

  gemm_qkv<<<dim3(M_TOT / 256, DIM / 256, 3), 512, 0, stream>>>(
      Qb, Kb, Vb, wqb, wkb, wvb, bq, bk, bv, qp, kp, vp);

  flash_attn<<<dim3(B_SZ * NH, T_SEQ / 256), 512, 0, stream>>>(qp, kp, vp, aop);

  gemm_out<<<dim3(M_TOT / 128, DIM / 128), 256, 0, stream>>>(aop, wob, bo, out);
}

// Round 5
// 308.177 us; speedup vs baseline: 1.0524x; 1.0524x over previous
//
#include <hip/hip_runtime.h>
#include <stdint.h>

// Problem constants
#define B_SZ  4
#define T_SEQ 2048
#define DIM   1024
#define NH    16
#define HD    64
#define M_TOT (B_SZ * T_SEQ)   // 8192

typedef unsigned short u16;
typedef unsigned long long u64;
typedef __attribute__((ext_vector_type(8))) __bf16 bf16x8;   // MFMA A/B frag (4 VGPR)
typedef __attribute__((ext_vector_type(4))) float  floatx4;  // MFMA C/D frag 16x16
typedef __attribute__((ext_vector_type(16))) float floatx16; // MFMA C/D frag 32x32

#define SCL_Q (0.125f * 1.44269504089f)   // 1/sqrt(HD) * log2(e), folded into q

__device__ __forceinline__ u16 f2bf(float f) {
  union { float f; uint32_t u; } v; v.f = f;
  uint32_t r = v.u + 0x7fffu + ((v.u >> 16) & 1u);   // RNE
  return (u16)(r >> 16);
}

// async global->LDS, 16B per lane; LDS dest = uniform base + lane*16
__device__ __forceinline__ void gl_lds16(const void* g, void* l) {
  __builtin_amdgcn_global_load_lds(
      (const __attribute__((address_space(1))) uint32_t*)g,
      (__attribute__((address_space(3))) uint32_t*)l, 16, 0, 0);
}

// ---------------------------------------------------------------- converts
// One dispatch converts all 7 f32 tensors to bf16:
// y=0..3 -> weights (1M elems), y=4..6 -> activations Q,K,V (8M elems)
__global__ __launch_bounds__(256) void cvt_all(
    const float* __restrict__ s0, const float* __restrict__ s1,
    const float* __restrict__ s2, const float* __restrict__ s3,
    const float* __restrict__ s4, const float* __restrict__ s5,
    const float* __restrict__ s6,
    u16* __restrict__ d0, u16* __restrict__ d1, u16* __restrict__ d2,
    u16* __restrict__ d3, u16* __restrict__ d4, u16* __restrict__ d5,
    u16* __restrict__ d6) {
  const float* s; u16* d; int n;
  switch (blockIdx.y) {
    case 0: s = s0; d = d0; n = DIM * DIM; break;
    case 1: s = s1; d = d1; n = DIM * DIM; break;
    case 2: s = s2; d = d2; n = DIM * DIM; break;
    case 3: s = s3; d = d3; n = DIM * DIM; break;
    case 4: s = s4; d = d4; n = M_TOT * DIM; break;
    case 5: s = s5; d = d5; n = M_TOT * DIM; break;
    default: s = s6; d = d6; n = M_TOT * DIM; break;
  }
  int i = (blockIdx.x * 256 + threadIdx.x) * 8;
  if (i >= n) return;
  float4 a = *(const float4*)(s + i);
  float4 b = *(const float4*)(s + i + 4);
  uint4 o;
  o.x = (uint32_t)f2bf(a.x) | ((uint32_t)f2bf(a.y) << 16);
  o.y = (uint32_t)f2bf(a.z) | ((uint32_t)f2bf(a.w) << 16);
  o.z = (uint32_t)f2bf(b.x) | ((uint32_t)f2bf(b.y) << 16);
  o.w = (uint32_t)f2bf(b.z) | ((uint32_t)f2bf(b.w) << 16);
  *(uint4*)(d + i) = o;
}

// ---------------------------------------------------------------- QKV GEMM
// REVERTED to the proven 128x128/BK=64 2-barrier version (round-1/2, 75us,
// 687 TF). The 8-phase 256^2 graft measured 92us: 1 block/CU (no co-resident
// overlap), 1.5 dispatch rounds (tail), and +32MB scatter write traffic.
// At these shapes multi-block/CU beats deep pipelining.
#define BKG 64
__global__ __launch_bounds__(256) void gemm_qkv(
    const u16* __restrict__ Qb, const u16* __restrict__ Kb,
    const u16* __restrict__ Vb,
    const u16* __restrict__ Wq, const u16* __restrict__ Wk,
    const u16* __restrict__ Wv,
    const float* __restrict__ bq, const float* __restrict__ bk,
    const float* __restrict__ bv,
    u16* __restrict__ qo, u16* __restrict__ ko, u16* __restrict__ vo) {
  const u16* A; const u16* Bw; const float* bias; u16* Co;
  if (blockIdx.z == 0)      { A = Qb; Bw = Wq; bias = bq; Co = qo; }
  else if (blockIdx.z == 1) { A = Kb; Bw = Wk; bias = bk; Co = ko; }
  else                      { A = Vb; Bw = Wv; bias = bv; Co = vo; }

  __shared__ u16 As[128 * 64];
  __shared__ u16 Bs[128 * 64];

  const int tid  = threadIdx.x;
  const int wave = tid >> 6, lane = tid & 63;
  const int quad = lane >> 4, l16 = lane & 15;
  const int wm = wave >> 1, wn = wave & 1;
  const int m0 = blockIdx.x * 128, n0 = blockIdx.y * 128;

  const floatx4 FZ = {0.f, 0.f, 0.f, 0.f};
  floatx4 acc[4][4];
#pragma unroll
  for (int mt = 0; mt < 4; ++mt)
#pragma unroll
    for (int nt = 0; nt < 4; ++nt) acc[mt][nt] = FZ;

  for (int k0 = 0; k0 < DIM; k0 += BKG) {
    __syncthreads();
#pragma unroll
    for (int j = 0; j < 4; ++j) {
      int pc = j * 256 + tid;
      int r = pc >> 3, c = pc & 7;
      int sc = c ^ (r & 7);
      gl_lds16(A  + (size_t)(m0 + r) * DIM + k0 + sc * 8,
               &As[(j * 256 + wave * 64) * 8]);
      gl_lds16(Bw + (size_t)(n0 + r) * DIM + k0 + sc * 8,
               &Bs[(j * 256 + wave * 64) * 8]);
    }
    __syncthreads();

#pragma unroll
    for (int kk = 0; kk < 2; ++kk) {
      bf16x8 af[4], bfr[4];
#pragma unroll
      for (int mt = 0; mt < 4; ++mt) {
        int ra = wm * 64 + mt * 16 + l16;
        af[mt] = *(const bf16x8*)&As[ra * 64 + (((kk * 4 + quad) ^ (ra & 7)) * 8)];
      }
#pragma unroll
      for (int nt = 0; nt < 4; ++nt) {
        int rb = wn * 64 + nt * 16 + l16;
        bfr[nt] = *(const bf16x8*)&Bs[rb * 64 + (((kk * 4 + quad) ^ (rb & 7)) * 8)];
      }
#pragma unroll
      for (int mt = 0; mt < 4; ++mt)
#pragma unroll
        for (int nt = 0; nt < 4; ++nt)
          acc[mt][nt] = __builtin_amdgcn_mfma_f32_16x16x32_bf16(
              af[mt], bfr[nt], acc[mt][nt], 0, 0, 0);
    }
  }

  if (blockIdx.z == 2) {
    // V: transposed store to [B,H,HD,T], 8B packed (4 consecutive t)
#pragma unroll
    for (int nt = 0; nt < 4; ++nt) {
      int n = n0 + wn * 64 + nt * 16 + l16;
      float bb = bias[n];
      int h = n >> 6, hd = n & 63;
#pragma unroll
      for (int mt = 0; mt < 4; ++mt) {
        int mbase = m0 + wm * 64 + mt * 16 + quad * 4;
        int b = mbase >> 11, t = mbase & (T_SEQ - 1);
        u64 pk = 0;
#pragma unroll
        for (int r = 0; r < 4; ++r)
          pk |= (u64)f2bf(acc[mt][nt][r] + bb) << (16 * r);
        *(u64*)&Co[((size_t)((b * NH + h) * HD + hd)) * T_SEQ + t] = pk;
      }
    }
  } else {
    // Q/K: +bias (Q also * SCL_Q), bf16, scatter to [B,H,T,HD]
    const float sc = (blockIdx.z == 0) ? SCL_Q : 1.0f;
#pragma unroll
    for (int nt = 0; nt < 4; ++nt) {
      int n = n0 + wn * 64 + nt * 16 + l16;
      float bb = bias[n];
      int h = n >> 6, hd = n & 63;
#pragma unroll
      for (int mt = 0; mt < 4; ++mt) {
#pragma unroll
        for (int r = 0; r < 4; ++r) {
          int m = m0 + wm * 64 + mt * 16 + quad * 4 + r;
          int b = m >> 11, t = m & (T_SEQ - 1);
          Co[((size_t)(b * NH + h) * T_SEQ + t) * HD + hd] =
              f2bf((acc[mt][nt][r] + bb) * sc);
        }
      }
    }
  }
}

// ---------------------------------------------------------------- flash attn
// v4: 4 waves x 64 q-cols per wave (two 32-col q-sets per lane), 256 thr.
// K and V LDS fragments are read ONCE per wave and feed BOTH q-sets' MFMAs
// -> block-tile LDS traffic halves vs v3 (64 vs 128 ds_read_b128) at equal
// FLOPs. Pipeline unchanged: 3-deep K/V, raw s_barrier + counted vmcnt(4)
// (4 stage ops/tile/wave now). All 512 blocks co-resident (2/CU, 48KB LDS,
// <=256 VGPR via launch_bounds(256,2)); heavy+light qt pairing -> 36
// tiles/CU balanced. Fixed-max softmax (exact, log2-domain) as verified.
__global__ __launch_bounds__(256, 2) void flash_attn(
    const u16* __restrict__ qp, const u16* __restrict__ kp,
    const u16* __restrict__ vp, u16* __restrict__ ao) {
  const int bh = blockIdx.x;                       // 0..63
  const int y = blockIdx.y;                        // 0..7
  const int qt = (y < 4) ? (7 - y) : (y - 4);      // heavy first + pairing
  const int b = bh >> 4, h = bh & 15;
  const u16* Qg = qp + (size_t)bh * T_SEQ * HD;
  const u16* Kg = kp + (size_t)bh * T_SEQ * HD;
  const u16* Vg = vp + (size_t)bh * HD * T_SEQ;    // [hd][t]

  __shared__ u16 lds[6][64 * 64];   // {K,V} x 3-deep, 48 KB

  const int tid = threadIdx.x, wave = tid >> 6, lane = tid & 63;
  const int hi = lane >> 5, c31 = lane & 31;
  const int lr8 = lane >> 3, lc8 = lane & 7;

  const int wbase = qt * 256 + wave * 64;   // wave's 64 q rows
  const int qrowA = wbase + c31;            // q-set A
  const int qrowB = qrowA + 32;             // q-set B

  // ---- Q B-frags for both sets straight from global FIRST (oldest vmem)
  bf16x8 bqA[4], bqB[4];
#pragma unroll
  for (int cth = 0; cth < 4; ++cth) {
    bqA[cth] = *(const bf16x8*)(Qg + (size_t)qrowA * HD + cth * 16 + hi * 8);
    bqB[cth] = *(const bf16x8*)(Qg + (size_t)qrowB * HD + cth * 16 + hi * 8);
  }

  const int nkb = 4 * qt + 4;   // kv tiles (>=4)

  // staging: with 4 waves, 2 calls per tensor per tile (rows i*32+wave*8+lr8)
#define STAGE_KV(kbidx, bufpair)                                              \
  {                                                                           \
    const u16* Kgk = Kg + (size_t)(kbidx) * 64 * HD;                          \
    const u16* Vgk = Vg + (size_t)(kbidx) * 64;                               \
    _Pragma("unroll") for (int i_ = 0; i_ < 2; ++i_) {                        \
      int r_ = i_ * 32 + wave * 8 + lr8;                                      \
      int sc_ = lc8 ^ (r_ & 7);                                               \
      gl_lds16(Kgk + (size_t)r_ * HD + sc_ * 8,                               \
               &lds[(bufpair) * 2][(i_ * 32 + wave * 8) * 64]);               \
      gl_lds16(Vgk + (size_t)r_ * T_SEQ + sc_ * 8,                            \
               &lds[(bufpair) * 2 + 1][(i_ * 32 + wave * 8) * 64]);           \
    }                                                                         \
  }

  // ---- prologue: stage kv-tiles 0 and 1 (4 vmem ops per wave per tile)
  STAGE_KV(0, 0);
  STAGE_KV(1, 1);

  // keep Q frags live; they retire under the first vmcnt(4) (oldest ops)
  asm volatile("" :: "v"(bqA[0]), "v"(bqA[1]), "v"(bqA[2]), "v"(bqA[3]),
                     "v"(bqB[0]), "v"(bqB[1]), "v"(bqB[2]), "v"(bqB[3]));

  floatx16 oA0, oA1, oB0, oB1;   // O^T accum per set: hd 0..31 / 32..63
#pragma unroll
  for (int i = 0; i < 16; ++i) { oA0[i] = 0.f; oA1[i] = 0.f;
                                 oB0[i] = 0.f; oB1[i] = 0.f; }
  float l_pA = 0.f, l_pB = 0.f;  // lane-local softmax denominators

  // swizzled LDS element offsets for A-frag reads (lane-const, shared K/V)
  int koff[4];
#pragma unroll
  for (int x = 0; x < 4; ++x)
    koff[x] = c31 * 64 + (((x * 2 + hi) ^ (c31 & 7)) * 8);

  int pcb = 0;   // compute buffer-pair
  int psb = 2;   // next stage buffer-pair
  for (int kb = 0; kb < nkb; ++kb) {
    // retire own oldest tile's 4 loads, keep next tile's 4 in flight
    if (kb + 1 < nkb) asm volatile("s_waitcnt vmcnt(4)" ::: "memory");
    else              asm volatile("s_waitcnt vmcnt(0)" ::: "memory");
    __builtin_amdgcn_s_barrier();
    __builtin_amdgcn_sched_barrier(0);

    if (kb + 2 < nkb) {   // stage tile kb+2 (lands ~2 compute phases later)
      STAGE_KV(kb + 2, psb);
      psb = (psb == 2) ? 0 : psb + 1;
    }

    // wave fully above the diagonal -> skip compute (barriers stay uniform)
    if (kb * 64 <= wbase + 63) {
      const u16* Ks = &lds[pcb * 2][0];
      const u16* Vs = &lds[pcb * 2 + 1][0];

      // S^T = K Q^T for both q-sets; K frags read once, used twice
      floatx16 sA0, sA1, sB0, sB1;
#pragma unroll
      for (int i = 0; i < 16; ++i) { sA0[i] = 0.f; sA1[i] = 0.f;
                                     sB0[i] = 0.f; sB1[i] = 0.f; }
#pragma unroll
      for (int cth = 0; cth < 4; ++cth) {
        bf16x8 ka = *(const bf16x8*)&Ks[koff[cth]];
        bf16x8 kh = *(const bf16x8*)&Ks[koff[cth] + 32 * 64];
        sA0 = __builtin_amdgcn_mfma_f32_32x32x16_bf16(ka, bqA[cth], sA0, 0, 0, 0);
        sA1 = __builtin_amdgcn_mfma_f32_32x32x16_bf16(kh, bqA[cth], sA1, 0, 0, 0);
        sB0 = __builtin_amdgcn_mfma_f32_32x32x16_bf16(ka, bqB[cth], sB0, 0, 0, 0);
        sB1 = __builtin_amdgcn_mfma_f32_32x32x16_bf16(kh, bqB[cth], sB1, 0, 0, 0);
      }

      // causal mask only on diagonal-overlapping tiles
      if (kb * 64 + 63 > wbase) {
        int kvb = kb * 64 + 4 * hi;
#pragma unroll
        for (int r = 0; r < 16; ++r) {
          int kvr = kvb + (r & 3) + 8 * (r >> 2);
          if (kvr > qrowA)      sA0[r] = -3e38f;
          if (kvr + 32 > qrowA) sA1[r] = -3e38f;
          if (kvr > qrowB)      sB0[r] = -3e38f;
          if (kvr + 32 > qrowB) sB1[r] = -3e38f;
        }
      }

      // fixed-max softmax: p = exp2(s); pack kv-adjacent pairs to bf16 u32
      uint32_t pkA0[8], pkA1[8], pkB0[8], pkB1[8];
      float rsA = 0.f, rsB = 0.f;
#pragma unroll
      for (int rr = 0; rr < 8; ++rr) {
        union { float f; uint32_t u; } x0, x1, y0, y1;
        x0.f = __builtin_amdgcn_exp2f(sA0[2 * rr]);
        x1.f = __builtin_amdgcn_exp2f(sA0[2 * rr + 1]);
        y0.f = __builtin_amdgcn_exp2f(sA1[2 * rr]);
        y1.f = __builtin_amdgcn_exp2f(sA1[2 * rr + 1]);
        rsA += (x0.f + x1.f) + (y0.f + y1.f);
        pkA0[rr] = __builtin_amdgcn_perm(x1.u, x0.u, 0x07060302);
        pkA1[rr] = __builtin_amdgcn_perm(y1.u, y0.u, 0x07060302);
        x0.f = __builtin_amdgcn_exp2f(sB0[2 * rr]);
        x1.f = __builtin_amdgcn_exp2f(sB0[2 * rr + 1]);
        y0.f = __builtin_amdgcn_exp2f(sB1[2 * rr]);
        y1.f = __builtin_amdgcn_exp2f(sB1[2 * rr + 1]);
        rsB += (x0.f + x1.f) + (y0.f + y1.f);
        pkB0[rr] = __builtin_amdgcn_perm(x1.u, x0.u, 0x07060302);
        pkB1[rr] = __builtin_amdgcn_perm(y1.u, y0.u, 0x07060302);
      }
      l_pA += rsA;
      l_pB += rsB;

      // PV: O^T += V^T P^T; V frags read once, used by both q-sets
#pragma unroll
      for (int cc = 0; cc < 4; ++cc) {
        const uint32_t* pA = (cc & 2) ? pkA1 : pkA0;
        const uint32_t* pB = (cc & 2) ? pkB1 : pkB0;
        const int e4 = (cc & 1) * 4;
        auto a0 = __builtin_amdgcn_permlane32_swap(pA[e4 + 0], pA[e4 + 2],
                                                   false, false);
        auto a1 = __builtin_amdgcn_permlane32_swap(pA[e4 + 1], pA[e4 + 3],
                                                   false, false);
        auto b0 = __builtin_amdgcn_permlane32_swap(pB[e4 + 0], pB[e4 + 2],
                                                   false, false);
        auto b1 = __builtin_amdgcn_permlane32_swap(pB[e4 + 1], pB[e4 + 3],
                                                   false, false);
        union { uint32_t u[4]; bf16x8 v; } bpA, bpB;
        bpA.u[0] = a0[0]; bpA.u[1] = a1[0]; bpA.u[2] = a0[1]; bpA.u[3] = a1[1];
        bpB.u[0] = b0[0]; bpB.u[1] = b1[0]; bpB.u[2] = b0[1]; bpB.u[3] = b1[1];
        bf16x8 va = *(const bf16x8*)&Vs[koff[cc]];
        bf16x8 vb = *(const bf16x8*)&Vs[koff[cc] + 32 * 64];
        oA0 = __builtin_amdgcn_mfma_f32_32x32x16_bf16(va, bpA.v, oA0, 0, 0, 0);
        oA1 = __builtin_amdgcn_mfma_f32_32x32x16_bf16(vb, bpA.v, oA1, 0, 0, 0);
        oB0 = __builtin_amdgcn_mfma_f32_32x32x16_bf16(va, bpB.v, oB0, 0, 0, 0);
        oB1 = __builtin_amdgcn_mfma_f32_32x32x16_bf16(vb, bpB.v, oB1, 0, 0, 0);
      }
    }
    pcb = (pcb == 2) ? 0 : pcb + 1;
  }
#undef STAGE_KV

  // ---- epilogue: cross-half l reduction, O = O^T/l -> bf16 [B,T,D]
  {
    float lA = l_pA + __shfl_xor(l_pA, 32);
    float lB = l_pB + __shfl_xor(l_pB, 32);
    float invA = 1.0f / lA, invB = 1.0f / lB;
    const size_t obaseA = (size_t)(b * T_SEQ + qrowA) * DIM + h * HD;
    const size_t obaseB = obaseA + (size_t)32 * DIM;
#pragma unroll
    for (int u4 = 0; u4 < 4; ++u4) {
      u64 wA0 = 0, wA1 = 0, wB0 = 0, wB1 = 0;
#pragma unroll
      for (int r = 0; r < 4; ++r) {
        wA0 |= (u64)f2bf(oA0[4 * u4 + r] * invA) << (16 * r);
        wA1 |= (u64)f2bf(oA1[4 * u4 + r] * invA) << (16 * r);
        wB0 |= (u64)f2bf(oB0[4 * u4 + r] * invB) << (16 * r);
        wB1 |= (u64)f2bf(oB1[4 * u4 + r] * invB) << (16 * r);
      }
      *(u64*)&ao[obaseA + 8 * u4 + 4 * hi] = wA0;
      *(u64*)&ao[obaseA + 32 + 8 * u4 + 4 * hi] = wA1;
      *(u64*)&ao[obaseB + 8 * u4 + 4 * hi] = wB0;
      *(u64*)&ao[obaseB + 32 + 8 * u4 + 4 * hi] = wB1;
    }
  }
}

// ---------------------------------------------------------------- out GEMM
__global__ __launch_bounds__(256) void gemm_out(
    const u16* __restrict__ Ain, const u16* __restrict__ Wo,
    const float* __restrict__ bo, float* __restrict__ out) {
  __shared__ u16 As[128 * 64];
  __shared__ u16 Bs[128 * 64];

  const int tid  = threadIdx.x;
  const int wave = tid >> 6, lane = tid & 63;
  const int quad = lane >> 4, l16 = lane & 15;
  const int wm = wave >> 1, wn = wave & 1;
  const int m0 = blockIdx.x * 128, n0 = blockIdx.y * 128;

  const floatx4 FZ = {0.f, 0.f, 0.f, 0.f};
  floatx4 acc[4][4];
#pragma unroll
  for (int mt = 0; mt < 4; ++mt)
#pragma unroll
    for (int nt = 0; nt < 4; ++nt) acc[mt][nt] = FZ;

  for (int k0 = 0; k0 < DIM; k0 += BKG) {
    __syncthreads();
#pragma unroll
    for (int j = 0; j < 4; ++j) {
      int pc = j * 256 + tid;
      int r = pc >> 3, c = pc & 7;
      int sc = c ^ (r & 7);
      gl_lds16(Ain + (size_t)(m0 + r) * DIM + k0 + sc * 8,
               &As[(j * 256 + wave * 64) * 8]);
      gl_lds16(Wo  + (size_t)(n0 + r) * DIM + k0 + sc * 8,
               &Bs[(j * 256 + wave * 64) * 8]);
    }
    __syncthreads();

#pragma unroll
    for (int kk = 0; kk < 2; ++kk) {
      bf16x8 af[4], bfr[4];
#pragma unroll
      for (int mt = 0; mt < 4; ++mt) {
        int ra = wm * 64 + mt * 16 + l16;
        af[mt] = *(const bf16x8*)&As[ra * 64 + (((kk * 4 + quad) ^ (ra & 7)) * 8)];
      }
#pragma unroll
      for (int nt = 0; nt < 4; ++nt) {
        int rb = wn * 64 + nt * 16 + l16;
        bfr[nt] = *(const bf16x8*)&Bs[rb * 64 + (((kk * 4 + quad) ^ (rb & 7)) * 8)];
      }
#pragma unroll
      for (int mt = 0; mt < 4; ++mt)
#pragma unroll
        for (int nt = 0; nt < 4; ++nt)
          acc[mt][nt] = __builtin_amdgcn_mfma_f32_16x16x32_bf16(
              af[mt], bfr[nt], acc[mt][nt], 0, 0, 0);
    }
  }

#pragma unroll
  for (int nt = 0; nt < 4; ++nt) {
    int n = n0 + wn * 64 + nt * 16 + l16;
    float bb = bo[n];
#pragma unroll
    for (int mt = 0; mt < 4; ++mt)
#pragma unroll
      for (int r = 0; r < 4; ++r) {
        int m = m0 + wm * 64 + mt * 16 + quad * 4 + r;
        out[(size_t)m * DIM + n] = acc[mt][nt][r] + bb;
      }
  }
}

// ---------------------------------------------------------------- launch
extern "C" void kernel_launch(void* const* d_in, const int* in_sizes, int n_in,
                              void* d_out, int out_size, void* d_ws,
                              size_t ws_size, hipStream_t stream) {
  const float* Q  = (const float*)d_in[0];
  const float* K  = (const float*)d_in[1];
  const float* V  = (const float*)d_in[2];
  // d_in[3] = mask: tril causal, implemented analytically in flash_attn
  const float* Wq = (const float*)d_in[4];
  const float* bq = (const float*)d_in[5];
  const float* Wk = (const float*)d_in[6];
  const float* bk = (const float*)d_in[7];
  const float* Wv = (const float*)d_in[8];
  const float* bv = (const float*)d_in[9];
  const float* Wo = (const float*)d_in[10];
  const float* bo = (const float*)d_in[11];
  float* out = (float*)d_out;

  // workspace layout (u16 elements), total ~120 MiB
  u16* wqb = (u16*)d_ws;
  u16* wkb = wqb + 1048576;
  u16* wvb = wkb + 1048576;
  u16* wob = wvb + 1048576;
  u16* Qb  = wob + 1048576;             // activations bf16 [B,T,D]
  u16* Kb  = Qb + (size_t)M_TOT * DIM;
  u16* Vb  = Kb + (size_t)M_TOT * DIM;
  u16* qp  = Vb + (size_t)M_TOT * DIM;  // projected [B,H,T,HD] (q pre-scaled)
  u16* kp  = qp + (size_t)M_TOT * DIM;  // [B,H,T,HD]
  u16* vp  = kp + (size_t)M_TOT * DIM;  // [B,H,HD,T]  (pre-transposed)
  u16* aop = vp + (size_t)M_TOT * DIM;  // attn out [B,T,D] bf16

  cvt_all<<<dim3(M_TOT * DIM / 2048, 7), 256, 0, stream>>>(
      Wq, Wk, Wv, Wo, Q, K, V, wqb, wkb, wvb, wob, Qb, Kb, Vb);

  gemm_qkv<<<dim3(M_TOT / 128, DIM / 128, 3), 256, 0, stream>>>(
      Qb, Kb, Vb, wqb, wkb, wvb, bq, bk, bv, qp, kp, vp);

  flash_attn<<<dim3(B_SZ * NH, T_SEQ / 256), 256, 0, stream>>>(qp, kp, vp, aop);

  gemm_out<<<dim3(M_TOT / 128, DIM / 128), 256, 0, stream>>>(aop, wob, bo, out);
}